// Round 6
// baseline (61.849 us; speedup 1.0000x reference)
//
#include <hip/hip_runtime.h>
#include <hip/hip_bf16.h>

#define EPS 0.1f
#define KSEL 16
#define KD 256

typedef __attribute__((ext_vector_type(4))) float f32x4;
typedef __attribute__((ext_vector_type(8))) short s16x8;
typedef __attribute__((ext_vector_type(4))) short s16x4;

__device__ inline s16x4 cvt4(f32x4 a) {
    // scalar casts -> compiler packs v_cvt_pk_bf16_f32 (m240: don't hand-write)
    s16x4 p;
    p[0] = __builtin_bit_cast(short, __float2bfloat16(a[0]));
    p[1] = __builtin_bit_cast(short, __float2bfloat16(a[1]));
    p[2] = __builtin_bit_cast(short, __float2bfloat16(a[2]));
    p[3] = __builtin_bit_cast(short, __float2bfloat16(a[3]));
    return p;
}

// C[m][n] = sum_k Q[m][k]*Nb[n][k].  Block tile 64(M) x 64(N), BK=64, nk=4.
// 256 threads = 4 waves (2x2), each wave a 32x32 sub-tile.
// Depth-2 REGISTER prefetch + double-buffered LDS. 32 KB LDS -> 5 blocks/CU.
// XCD-bijective block swizzle: each XCD owns 256 contiguous blocks (4 row-panels).
// Epilogue: C -> LDS (reuse As, exactly 16 KB) -> f32x4 stores.
// Per-block max of max(s^2,(s-1)^2) -> bmax[nf].
struct PF { f32x4 a[4]; f32x4 b[4]; };   // 2 A-slots + 2 B-slots, 32 VGPR

__global__ __launch_bounds__(256, 2) void gemm_kernel(
    const float* __restrict__ Q, const float* __restrict__ Nb,
    float* __restrict__ dist, float* __restrict__ scor,
    float* __restrict__ bmax, int Nn)
{
    __shared__ __align__(16) char As[2][64 * 128];  // 64 rows x 64 bf16, swizzled
    __shared__ __align__(16) char Bs[2][64 * 128];

    const int t = threadIdx.x;         // 0..255
    const int lane = t & 63;
    const int wave = t >> 6;           // 0..3
    const int wr = wave >> 1;          // 0..1
    const int wc = wave & 1;           // 0..1

    // XCD-bijective swizzle: 2048 blocks, 8 XCDs -> XCD j gets nf in [j*256,(j+1)*256)
    const int flat = blockIdx.y * gridDim.x + blockIdx.x;   // grid = (64, 32)
    const int nf = (flat & 7) * 256 + (flat >> 3);
    const int brow = (nf >> 6) * 64;   // by in [0,32)
    const int bcol = (nf & 63) * 64;   // bx in [0,64)

    f32x4 acc[2][2] = {};
    PF R0, R1;

    // slot map: tile = 64 rows x 8 groups of 8 floats (16B bf16). 512 slots;
    // thread t takes slots t and t+256: rows r0=t>>3 (0..31), r1=32+r0, p=t&7.
    const int r0 = t >> 3, r1 = 32 + (t >> 3), p = t & 7;

    auto issue = [&](PF& R, int kt) {
        const float* qa0 = &Q[(size_t)(brow + r0) * KD + kt * 64 + p * 8];
        R.a[0] = *reinterpret_cast<const f32x4*>(qa0);
        R.a[1] = *reinterpret_cast<const f32x4*>(qa0 + 4);
        const float* qa1 = &Q[(size_t)(brow + r1) * KD + kt * 64 + p * 8];
        R.a[2] = *reinterpret_cast<const f32x4*>(qa1);
        R.a[3] = *reinterpret_cast<const f32x4*>(qa1 + 4);
        const float* qb0 = &Nb[(size_t)(bcol + r0) * KD + kt * 64 + p * 8];
        R.b[0] = *reinterpret_cast<const f32x4*>(qb0);
        R.b[1] = *reinterpret_cast<const f32x4*>(qb0 + 4);
        const float* qb1 = &Nb[(size_t)(bcol + r1) * KD + kt * 64 + p * 8];
        R.b[2] = *reinterpret_cast<const f32x4*>(qb1);
        R.b[3] = *reinterpret_cast<const f32x4*>(qb1 + 4);
    };
    auto commit = [&](PF& R, int buf) {
        s16x8 v;
        s16x4 lo = cvt4(R.a[0]), hi = cvt4(R.a[1]);
        #pragma unroll
        for (int j = 0; j < 4; ++j) { v[j] = lo[j]; v[4 + j] = hi[j]; }
        *reinterpret_cast<s16x8*>(&As[buf][r0 * 128 + ((p * 16) ^ ((r0 & 7) << 4))]) = v;
        lo = cvt4(R.a[2]); hi = cvt4(R.a[3]);
        #pragma unroll
        for (int j = 0; j < 4; ++j) { v[j] = lo[j]; v[4 + j] = hi[j]; }
        *reinterpret_cast<s16x8*>(&As[buf][r1 * 128 + ((p * 16) ^ ((r1 & 7) << 4))]) = v;
        lo = cvt4(R.b[0]); hi = cvt4(R.b[1]);
        #pragma unroll
        for (int j = 0; j < 4; ++j) { v[j] = lo[j]; v[4 + j] = hi[j]; }
        *reinterpret_cast<s16x8*>(&Bs[buf][r0 * 128 + ((p * 16) ^ ((r0 & 7) << 4))]) = v;
        lo = cvt4(R.b[2]); hi = cvt4(R.b[3]);
        #pragma unroll
        for (int j = 0; j < 4; ++j) { v[j] = lo[j]; v[4 + j] = hi[j]; }
        *reinterpret_cast<s16x8*>(&Bs[buf][r1 * 128 + ((p * 16) ^ ((r1 & 7) << 4))]) = v;
    };
    auto mfma_step = [&](int buf) {
        #pragma unroll
        for (int ks = 0; ks < 2; ++ks) {
            int kb = ks * 64 + ((lane >> 4) << 4);
            s16x8 af[2], bf[2];
            #pragma unroll
            for (int m = 0; m < 2; ++m) {
                int r = wr * 32 + m * 16 + (lane & 15);
                af[m] = *reinterpret_cast<const s16x8*>(
                    &As[buf][r * 128 + (kb ^ ((r & 7) << 4))]);
            }
            #pragma unroll
            for (int n = 0; n < 2; ++n) {
                int r = wc * 32 + n * 16 + (lane & 15);
                bf[n] = *reinterpret_cast<const s16x8*>(
                    &Bs[buf][r * 128 + (kb ^ ((r & 7) << 4))]);
            }
            #pragma unroll
            for (int m = 0; m < 2; ++m)
                #pragma unroll
                for (int n = 0; n < 2; ++n)
                    acc[m][n] = __builtin_amdgcn_mfma_f32_16x16x32_bf16(
                        af[m], bf[n], acc[m][n], 0, 0, 0);
        }
    };

    // ---- pipeline: nk = 4 fixed (KD=256, BK=64) ----
    issue(R0, 0);
    issue(R1, 1);
    commit(R0, 0);            // waits R0 only (R1 stays in flight)
    __syncthreads();

    issue(R0, 2);             // in flight across step 0
    mfma_step(0);
    commit(R1, 1);
    __syncthreads();

    issue(R1, 3);             // in flight across step 1
    mfma_step(1);
    commit(R0, 0);
    __syncthreads();

    mfma_step(0);
    commit(R1, 1);
    __syncthreads();

    mfma_step(1);
    __syncthreads();   // all waves done reading As[1]/Bs[1] before Ct overwrite

    // ---- epilogue: C through As (exactly 16 KB = 64x64 f32) ----
    float* Ct = reinterpret_cast<float*>(&As[0][0]);
    float* wmax = reinterpret_cast<float*>(&Bs[0][0]);   // Bs dead now
    #pragma unroll
    for (int m = 0; m < 2; ++m)
        #pragma unroll
        for (int n = 0; n < 2; ++n)
            #pragma unroll
            for (int j = 0; j < 4; ++j) {
                int row = wr * 32 + m * 16 + ((lane >> 4) << 2) + j;
                int col = wc * 32 + n * 16 + (lane & 15);
                Ct[row * 64 + col] = acc[m][n][j];
            }
    __syncthreads();

    float mx = 0.0f;
    #pragma unroll
    for (int it = 0; it < 4; ++it) {
        int r = wave * 16 + it * 4 + (lane >> 4);
        int c = (lane & 15) * 4;
        f32x4 v = *reinterpret_cast<f32x4*>(&Ct[r * 64 + c]);
        f32x4 s4;
        #pragma unroll
        for (int j = 0; j < 4; ++j) {
            float s = 1.0f - v[j];
            s4[j] = s;
            mx = fmaxf(mx, fmaxf(s * s, (s - 1.0f) * (s - 1.0f)));
        }
        size_t o = (size_t)(brow + r) * Nn + bcol + c;
        *reinterpret_cast<f32x4*>(&dist[o]) = v;
        *reinterpret_cast<f32x4*>(&scor[o]) = s4;
    }

    #pragma unroll
    for (int off = 32; off; off >>= 1) mx = fmaxf(mx, __shfl_xor(mx, off));
    if (lane == 0) wmax[wave] = mx;
    __syncthreads();
    if (t == 0) {
        float m2 = fmaxf(fmaxf(wmax[0], wmax[1]), fmaxf(wmax[2], wmax[3]));
        bmax[nf] = m2;
    }
}

// One block (256 threads) per query row. 2-column Sinkhorn fixed point:
// rho <- rho*(nu1/nu0)*W/(n-W),  W(rho)=sum_i 1/(1+rho*R_i),
// R_i = exp((2*s_i-1)/(M*EPS)).  Output: top_k_i = 1/(1+rho*R_i), masked.
// First reduces the per-block maxima to get M = C.max.
__global__ __launch_bounds__(256) void sinkhorn_kernel(
    const float* __restrict__ scor, float* __restrict__ out0,
    const float* __restrict__ bmax, int Nn, int nBmax)
{
    const int b = blockIdx.x;
    const int t = threadIdx.x;
    const int lane = t & 63;
    const int wave = t >> 6;
    __shared__ float sred[4];
    __shared__ float srho;
    __shared__ float sM;

    // global C.max from per-block maxima (L2-resident)
    float m = 0.0f;
    for (int i = t; i < nBmax; i += 256) m = fmaxf(m, bmax[i]);
    #pragma unroll
    for (int off = 32; off; off >>= 1) m = fmaxf(m, __shfl_xor(m, off));
    if (lane == 0) sred[wave] = m;
    __syncthreads();
    if (t == 0) sM = fmaxf(fmaxf(sred[0], sred[1]), fmaxf(sred[2], sred[3]));
    __syncthreads();
    const float Mmax = sM;

    const float invME = 1.0f / (Mmax * EPS);
    const float nuRatio = (float)(Nn - KSEL) / (float)KSEL;
    const float fn = (float)Nn;

    const float* row = scor + (size_t)b * Nn;
    float R[16];
    #pragma unroll
    for (int i = 0; i < 4; ++i) {
        f32x4 s4 = *reinterpret_cast<const f32x4*>(&row[(i * 256 + t) * 4]);
        #pragma unroll
        for (int j = 0; j < 4; ++j)
            R[i * 4 + j] = __expf((2.0f * s4[j] - 1.0f) * invME);
    }

    float rho = 1.0f;   // g0 = g1 = 0 initial condition
    for (int it = 0; it < 12; ++it) {
        float w = 0.0f;
        #pragma unroll
        for (int i = 0; i < 16; ++i)
            w += __builtin_amdgcn_rcpf(fmaf(rho, R[i], 1.0f));
        #pragma unroll
        for (int off = 32; off; off >>= 1) w += __shfl_xor(w, off);
        if (lane == 0) sred[wave] = w;
        __syncthreads();
        if (t == 0) {
            float W = sred[0] + sred[1] + sred[2] + sred[3];
            srho = rho * nuRatio * W / (fn - W);
        }
        __syncthreads();
        rho = srho;
    }

    float* orow = out0 + (size_t)b * Nn;
    #pragma unroll
    for (int i = 0; i < 4; ++i) {
        f32x4 v4;
        #pragma unroll
        for (int j = 0; j < 4; ++j) {
            float v = 1.0f / fmaf(rho, R[i * 4 + j], 1.0f);
            v4[j] = (v < 0.3f) ? 0.0f : v;
        }
        *reinterpret_cast<f32x4*>(&orow[(i * 256 + t) * 4]) = v4;
    }
}

extern "C" void kernel_launch(void* const* d_in, const int* in_sizes, int n_in,
                              void* d_out, int out_size, void* d_ws, size_t ws_size,
                              hipStream_t stream) {
    const float* Q  = (const float*)d_in[0];
    const float* Nb = (const float*)d_in[1];
    const int Mrows = in_sizes[0] / KD;   // 2048
    const int Nn    = in_sizes[1] / KD;   // 4096

    float* out0 = (float*)d_out;                       // top_k_seq
    float* dist = out0 + (size_t)Mrows * Nn;           // distances
    float* scor = dist + (size_t)Mrows * Nn;           // scores
    float* bmax = (float*)d_ws;                        // per-block maxima

    dim3 g1(Nn / 64, Mrows / 64);                      // 64 x 32 = 2048 blocks
    gemm_kernel<<<g1, 256, 0, stream>>>(Q, Nb, dist, scor, bmax, Nn);
    sinkhorn_kernel<<<Mrows, 256, 0, stream>>>(scor, out0, bmax, Nn,
                                               g1.x * g1.y);
}

// Round 7
// 53.924 us; speedup vs baseline: 1.1470x; 1.1470x over previous
//
#include <hip/hip_runtime.h>
#include <hip/hip_bf16.h>

#define EPS 0.1f
#define KSEL 16
#define KD 256

typedef __attribute__((ext_vector_type(4))) float f32x4;
typedef __attribute__((ext_vector_type(8))) short s16x8;
typedef __attribute__((ext_vector_type(4))) short s16x4;

__device__ inline s16x4 cvt4(f32x4 a) {
    s16x4 p;
    p[0] = __builtin_bit_cast(short, __float2bfloat16(a[0]));
    p[1] = __builtin_bit_cast(short, __float2bfloat16(a[1]));
    p[2] = __builtin_bit_cast(short, __float2bfloat16(a[2]));
    p[3] = __builtin_bit_cast(short, __float2bfloat16(a[3]));
    return p;
}

// ---------------------------------------------------------------------------
// Prep: convert Q (2048x256) and Nb (4096x256) f32 -> bf16 into d_ws, stored
// PRE-SWIZZLED in tile-slot order so the GEMM can DMA them into LDS linearly
// (global_load_lds needs linear LDS dest; swizzle lives in the global layout).
// Q slots:  ((panel*4+kt)*1024 + s) ; panel = row/128, s = (row%128)*8 + c16',
//           c16' = c16 ^ (row&7)  (16-byte groups of 8 bf16)
// Nb slots: ((panel*4+kt)*512  + s) ; panel = row/64
// ---------------------------------------------------------------------------
__global__ __launch_bounds__(256) void prep_kernel(
    const float* __restrict__ Q, const float* __restrict__ Nb,
    short* __restrict__ Qb, short* __restrict__ Nbb)
{
    int gid = blockIdx.x * 256 + threadIdx.x;   // 196608 threads total
    const float* src;
    short* dst;
    if (gid < 65536) {                 // Q: 16 panels x 4 kt x 1024 slots
        int s = gid & 1023, pk = gid >> 10;
        int kt = pk & 3, panel = pk >> 2;
        int row = panel * 128 + (s >> 3);
        int c16 = (s & 7) ^ ((s >> 3) & 7);
        src = &Q[(size_t)row * KD + kt * 64 + c16 * 8];
        dst = &Qb[(size_t)gid * 8];
    } else {                           // Nb: 64 panels x 4 kt x 512 slots
        int g = gid - 65536;
        int s = g & 511, pk = g >> 9;
        int kt = pk & 3, panel = pk >> 2;
        int row = panel * 64 + (s >> 3);
        int c16 = (s & 7) ^ ((s >> 3) & 7);
        src = &Nb[(size_t)row * KD + kt * 64 + c16 * 8];
        dst = &Nbb[(size_t)g * 8];
    }
    f32x4 a = *reinterpret_cast<const f32x4*>(src);
    f32x4 b = *reinterpret_cast<const f32x4*>(src + 4);
    s16x4 lo = cvt4(a), hi = cvt4(b);
    s16x8 v;
    #pragma unroll
    for (int j = 0; j < 4; ++j) { v[j] = lo[j]; v[4 + j] = hi[j]; }
    *reinterpret_cast<s16x8*>(dst) = v;
}

// ---------------------------------------------------------------------------
// GEMM: C[m][n] = sum_k Q[m][k]*Nb[n][k].  Tile 128(M) x 64(N), BK=64, nk=4.
// 512 threads = 8 waves (4x2), wave sub-tile 32x32.  Staging = pure DMA:
// 3x global_load_lds_dwordx4 per thread per K-step (no cvt, no reg roundtrip,
// no ds_write).  Double-buffered LDS, one barrier per K-step (m97 structure).
// Epilogue: C -> LDS (As, 32 KB dead) -> f32x4 stores; per-block max -> bmax.
// ---------------------------------------------------------------------------
__global__ __launch_bounds__(512, 6) void gemm_kernel(
    const short* __restrict__ Qb, const short* __restrict__ Nbb,
    float* __restrict__ dist, float* __restrict__ scor,
    float* __restrict__ bmax, int Nn)
{
    __shared__ __align__(16) char As[2][16384];  // 128 rows x 128B, swizzled
    __shared__ __align__(16) char Bs[2][8192];   // 64 rows x 128B, swizzled
    __shared__ float wmax[8];

    const int t = threadIdx.x;
    const int lane = t & 63;
    const int wave = t >> 6;
    const int wr = wave >> 1;          // 0..3
    const int wc = wave & 1;           // 0..1
    const int by = blockIdx.y, bx = blockIdx.x;
    const int brow = by * 128, bcol = bx * 64;

    f32x4 acc[2][2] = {};

    auto stage = [&](int buf, int kt) {
        const char* sa = reinterpret_cast<const char*>(Qb) + ((size_t)(by * 4 + kt) << 14);
        const char* sb = reinterpret_cast<const char*>(Nbb) + ((size_t)(bx * 4 + kt) << 13);
        // A: slots t and t+512 ; dest = wave-uniform base, HW adds lane*16
        __builtin_amdgcn_global_load_lds(
            (const __attribute__((address_space(1))) void*)(sa + t * 16),
            (__attribute__((address_space(3))) void*)(&As[buf][wave * 1024]),
            16, 0, 0);
        __builtin_amdgcn_global_load_lds(
            (const __attribute__((address_space(1))) void*)(sa + (512 + t) * 16),
            (__attribute__((address_space(3))) void*)(&As[buf][8192 + wave * 1024]),
            16, 0, 0);
        // B: slot t
        __builtin_amdgcn_global_load_lds(
            (const __attribute__((address_space(1))) void*)(sb + t * 16),
            (__attribute__((address_space(3))) void*)(&Bs[buf][wave * 1024]),
            16, 0, 0);
    };
    auto mfma_step = [&](int buf) {
        #pragma unroll
        for (int ks = 0; ks < 2; ++ks) {
            int kb = ks * 64 + ((lane >> 4) << 4);
            s16x8 af[2], bf[2];
            #pragma unroll
            for (int m = 0; m < 2; ++m) {
                int r = wr * 32 + m * 16 + (lane & 15);
                af[m] = *reinterpret_cast<const s16x8*>(
                    &As[buf][r * 128 + (kb ^ ((r & 7) << 4))]);
            }
            #pragma unroll
            for (int n = 0; n < 2; ++n) {
                int r = wc * 32 + n * 16 + (lane & 15);
                bf[n] = *reinterpret_cast<const s16x8*>(
                    &Bs[buf][r * 128 + (kb ^ ((r & 7) << 4))]);
            }
            #pragma unroll
            for (int m = 0; m < 2; ++m)
                #pragma unroll
                for (int n = 0; n < 2; ++n)
                    acc[m][n] = __builtin_amdgcn_mfma_f32_16x16x32_bf16(
                        af[m], bf[n], acc[m][n], 0, 0, 0);
        }
    };

    // m97-style pipeline: stage ahead, one barrier per K-step (vmcnt drained
    // by the compiler's pre-barrier waitcnt).
    stage(0, 0);
    __syncthreads();
    int cur = 0;
    #pragma unroll
    for (int kt = 0; kt < 4; ++kt) {
        if (kt < 3) stage(cur ^ 1, kt + 1);   // other buf: reads done at kt-1
        mfma_step(cur);
        __syncthreads();                       // next buf staged; cur reads done
        cur ^= 1;
    }

    // ---- epilogue: C through As (32 KB, dead after last barrier) ----
    float* Ct = reinterpret_cast<float*>(&As[0][0]);   // [128][64] f32
    #pragma unroll
    for (int m = 0; m < 2; ++m)
        #pragma unroll
        for (int n = 0; n < 2; ++n)
            #pragma unroll
            for (int j = 0; j < 4; ++j) {
                int row = wr * 32 + m * 16 + ((lane >> 4) << 2) + j;
                int col = wc * 32 + n * 16 + (lane & 15);
                Ct[row * 64 + col] = acc[m][n][j];
            }
    __syncthreads();

    float mx = 0.0f;
    #pragma unroll
    for (int it = 0; it < 4; ++it) {
        int r = wave * 16 + it * 4 + (lane >> 4);
        int c = (lane & 15) * 4;
        f32x4 v = *reinterpret_cast<f32x4*>(&Ct[r * 64 + c]);
        f32x4 s4;
        #pragma unroll
        for (int j = 0; j < 4; ++j) {
            float s = 1.0f - v[j];
            s4[j] = s;
            mx = fmaxf(mx, fmaxf(s * s, (s - 1.0f) * (s - 1.0f)));
        }
        size_t o = (size_t)(brow + r) * Nn + bcol + c;
        *reinterpret_cast<f32x4*>(&dist[o]) = v;
        *reinterpret_cast<f32x4*>(&scor[o]) = s4;
    }

    #pragma unroll
    for (int off = 32; off; off >>= 1) mx = fmaxf(mx, __shfl_xor(mx, off));
    if (lane == 0) wmax[wave] = mx;
    __syncthreads();
    if (t == 0) {
        float m2 = wmax[0];
        #pragma unroll
        for (int w = 1; w < 8; ++w) m2 = fmaxf(m2, wmax[w]);
        bmax[by * gridDim.x + bx] = m2;
    }
}

// One block (256 threads) per query row. 2-column Sinkhorn fixed point:
// rho <- rho*(nu1/nu0)*W/(n-W),  W(rho)=sum_i 1/(1+rho*R_i),
// R_i = exp((2*s_i-1)/(M*EPS)).  Output: top_k_i = 1/(1+rho*R_i), masked.
__global__ __launch_bounds__(256) void sinkhorn_kernel(
    const float* __restrict__ scor, float* __restrict__ out0,
    const float* __restrict__ bmax, int Nn, int nBmax)
{
    const int b = blockIdx.x;
    const int t = threadIdx.x;
    const int lane = t & 63;
    const int wave = t >> 6;
    __shared__ float sred[4];
    __shared__ float srho;
    __shared__ float sM;

    float m = 0.0f;
    for (int i = t; i < nBmax; i += 256) m = fmaxf(m, bmax[i]);
    #pragma unroll
    for (int off = 32; off; off >>= 1) m = fmaxf(m, __shfl_xor(m, off));
    if (lane == 0) sred[wave] = m;
    __syncthreads();
    if (t == 0) sM = fmaxf(fmaxf(sred[0], sred[1]), fmaxf(sred[2], sred[3]));
    __syncthreads();
    const float Mmax = sM;

    const float invME = 1.0f / (Mmax * EPS);
    const float nuRatio = (float)(Nn - KSEL) / (float)KSEL;
    const float fn = (float)Nn;

    const float* row = scor + (size_t)b * Nn;
    float R[16];
    #pragma unroll
    for (int i = 0; i < 4; ++i) {
        f32x4 s4 = *reinterpret_cast<const f32x4*>(&row[(i * 256 + t) * 4]);
        #pragma unroll
        for (int j = 0; j < 4; ++j)
            R[i * 4 + j] = __expf((2.0f * s4[j] - 1.0f) * invME);
    }

    float rho = 1.0f;
    for (int it = 0; it < 12; ++it) {
        float w = 0.0f;
        #pragma unroll
        for (int i = 0; i < 16; ++i)
            w += __builtin_amdgcn_rcpf(fmaf(rho, R[i], 1.0f));
        #pragma unroll
        for (int off = 32; off; off >>= 1) w += __shfl_xor(w, off);
        if (lane == 0) sred[wave] = w;
        __syncthreads();
        if (t == 0) {
            float W = sred[0] + sred[1] + sred[2] + sred[3];
            srho = rho * nuRatio * W / (fn - W);
        }
        __syncthreads();
        rho = srho;
    }

    float* orow = out0 + (size_t)b * Nn;
    #pragma unroll
    for (int i = 0; i < 4; ++i) {
        f32x4 v4;
        #pragma unroll
        for (int j = 0; j < 4; ++j) {
            float v = 1.0f / fmaf(rho, R[i * 4 + j], 1.0f);
            v4[j] = (v < 0.3f) ? 0.0f : v;
        }
        *reinterpret_cast<f32x4*>(&orow[(i * 256 + t) * 4]) = v4;
    }
}

extern "C" void kernel_launch(void* const* d_in, const int* in_sizes, int n_in,
                              void* d_out, int out_size, void* d_ws, size_t ws_size,
                              hipStream_t stream) {
    const float* Q  = (const float*)d_in[0];
    const float* Nb = (const float*)d_in[1];
    const int Mrows = in_sizes[0] / KD;   // 2048
    const int Nn    = in_sizes[1] / KD;   // 4096

    float* out0 = (float*)d_out;                       // top_k_seq
    float* dist = out0 + (size_t)Mrows * Nn;           // distances
    float* scor = dist + (size_t)Mrows * Nn;           // scores

    char* ws = (char*)d_ws;
    float* bmax = (float*)ws;                          // 4 KB
    short* Qb   = (short*)(ws + 4096);                 // 1 MB  (65536 x 16B)
    short* Nbb  = (short*)(ws + 4096 + (1 << 20));     // 2 MB  (131072 x 16B)

    prep_kernel<<<768, 256, 0, stream>>>(Q, Nb, Qb, Nbb);

    dim3 g1(Nn / 64, Mrows / 128);                     // 64 x 16 = 1024 blocks
    gemm_kernel<<<g1, 512, 0, stream>>>(Qb, Nbb, dist, scor, bmax, Nn);
    sinkhorn_kernel<<<Mrows, 256, 0, stream>>>(scor, out0, bmax, Nn,
                                               g1.x * g1.y);
}

// Round 8
// 45.538 us; speedup vs baseline: 1.3582x; 1.1842x over previous
//
#include <hip/hip_runtime.h>
#include <hip/hip_bf16.h>

#define EPS 0.1f
#define KSEL 16
#define KD 256

typedef __attribute__((ext_vector_type(4))) float f32x4;
typedef __attribute__((ext_vector_type(8))) short s16x8;
typedef __attribute__((ext_vector_type(4))) short s16x4;

__device__ inline s16x4 cvt4(f32x4 a) {
    // scalar casts -> compiler packs v_cvt_pk_bf16_f32 (m240: don't hand-write)
    s16x4 p;
    p[0] = __builtin_bit_cast(short, __float2bfloat16(a[0]));
    p[1] = __builtin_bit_cast(short, __float2bfloat16(a[1]));
    p[2] = __builtin_bit_cast(short, __float2bfloat16(a[2]));
    p[3] = __builtin_bit_cast(short, __float2bfloat16(a[3]));
    return p;
}

// C[m][n] = sum_k Q[m][k]*Nb[n][k].  Block tile 128(M) x 64(N), BK=64, nk=4.
// 512 threads = 8 waves (4x2), each wave a 32x32 sub-tile.
// Depth-2 REGISTER prefetch + double-buffered LDS (R5 structure, unchanged).
// Epilogue: C -> LDS -> f32x4 stores of DIST ONLY (scor moved to sinkhorn's
// contiguous streaming path).  Per-block max of max(s^2,(s-1)^2) -> bmax.
struct PF { f32x4 a[4]; f32x4 b[2]; };   // 6 x f32x4 = 24 VGPR per set

__global__ __launch_bounds__(512, 4) void gemm_kernel(
    const float* __restrict__ Q, const float* __restrict__ Nb,
    float* __restrict__ dist,
    float* __restrict__ bmax, int Nn)
{
    __shared__ __align__(16) char As[2][128 * 128];  // 128 rows x 64 bf16, swizzled
    __shared__ __align__(16) char Bs[2][64 * 128];   // 64 rows x 64 bf16, swizzled
    __shared__ float wmax[8];

    const int t = threadIdx.x;
    const int lane = t & 63;
    const int wave = t >> 6;
    const int wr = wave >> 1;          // 0..3
    const int wc = wave & 1;           // 0..1
    const int brow = blockIdx.y * 128;
    const int bcol = blockIdx.x * 64;

    f32x4 acc[2][2] = {};
    PF R0, R1;

    // slot map: A has 128 rows x 8 col-pairs(32B) = 1024 slots (t and t+512);
    // B has 64 rows x 8 pairs = 512 slots (t).  Each slot = 2 contiguous f32x4.
    const int ra0 = t >> 3, pa0 = t & 7;            // A slot 0 (rows 0..63)
    const int ra1 = (512 + t) >> 3, pa1 = t & 7;    // A slot 1 (rows 64..127)
    const int rb  = t >> 3, pb = t & 7;             // B slot

    auto issue = [&](PF& R, int kt) {
        const float* qa0 = &Q[(size_t)(brow + ra0) * KD + kt * 64 + pa0 * 8];
        R.a[0] = *reinterpret_cast<const f32x4*>(qa0);
        R.a[1] = *reinterpret_cast<const f32x4*>(qa0 + 4);
        const float* qa1 = &Q[(size_t)(brow + ra1) * KD + kt * 64 + pa1 * 8];
        R.a[2] = *reinterpret_cast<const f32x4*>(qa1);
        R.a[3] = *reinterpret_cast<const f32x4*>(qa1 + 4);
        const float* qb = &Nb[(size_t)(bcol + rb) * KD + kt * 64 + pb * 8];
        R.b[0] = *reinterpret_cast<const f32x4*>(qb);
        R.b[1] = *reinterpret_cast<const f32x4*>(qb + 4);
    };
    auto commit = [&](PF& R, int buf) {
        s16x8 v;
        s16x4 lo = cvt4(R.a[0]), hi = cvt4(R.a[1]);
        #pragma unroll
        for (int j = 0; j < 4; ++j) { v[j] = lo[j]; v[4 + j] = hi[j]; }
        *reinterpret_cast<s16x8*>(&As[buf][ra0 * 128 + ((pa0 * 16) ^ ((ra0 & 7) << 4))]) = v;
        lo = cvt4(R.a[2]); hi = cvt4(R.a[3]);
        #pragma unroll
        for (int j = 0; j < 4; ++j) { v[j] = lo[j]; v[4 + j] = hi[j]; }
        *reinterpret_cast<s16x8*>(&As[buf][ra1 * 128 + ((pa1 * 16) ^ ((ra1 & 7) << 4))]) = v;
        lo = cvt4(R.b[0]); hi = cvt4(R.b[1]);
        #pragma unroll
        for (int j = 0; j < 4; ++j) { v[j] = lo[j]; v[4 + j] = hi[j]; }
        *reinterpret_cast<s16x8*>(&Bs[buf][rb * 128 + ((pb * 16) ^ ((rb & 7) << 4))]) = v;
    };
    auto mfma_step = [&](int buf) {
        #pragma unroll
        for (int ks = 0; ks < 2; ++ks) {
            int kb = ks * 64 + ((lane >> 4) << 4);
            s16x8 af[2], bf[2];
            #pragma unroll
            for (int m = 0; m < 2; ++m) {
                int r = wr * 32 + m * 16 + (lane & 15);
                af[m] = *reinterpret_cast<const s16x8*>(
                    &As[buf][r * 128 + (kb ^ ((r & 7) << 4))]);
            }
            #pragma unroll
            for (int n = 0; n < 2; ++n) {
                int r = wc * 32 + n * 16 + (lane & 15);
                bf[n] = *reinterpret_cast<const s16x8*>(
                    &Bs[buf][r * 128 + (kb ^ ((r & 7) << 4))]);
            }
            #pragma unroll
            for (int m = 0; m < 2; ++m)
                #pragma unroll
                for (int n = 0; n < 2; ++n)
                    acc[m][n] = __builtin_amdgcn_mfma_f32_16x16x32_bf16(
                        af[m], bf[n], acc[m][n], 0, 0, 0);
        }
    };

    // ---- pipeline: nk = 4 fixed (KD=256, BK=64) ----
    issue(R0, 0);
    issue(R1, 1);
    commit(R0, 0);            // waits R0 only (R1 stays in flight)
    __syncthreads();

    issue(R0, 2);             // in flight across step 0
    mfma_step(0);
    commit(R1, 1);            // waits R1 (older than R0's new loads)
    __syncthreads();

    issue(R1, 3);             // in flight across step 1
    mfma_step(1);
    commit(R0, 0);
    __syncthreads();

    mfma_step(0);
    commit(R1, 1);
    __syncthreads();

    mfma_step(1);
    __syncthreads();   // REQUIRED: Ct spans As[0]+As[1]; all waves must finish
                       // their As[1]/Bs[1] fragment reads before overwrite.

    // ---- epilogue: transpose C through As (32 KB dead after barrier) ----
    float* Ct = reinterpret_cast<float*>(&As[0][0]);   // [128][64] f32
    #pragma unroll
    for (int m = 0; m < 2; ++m)
        #pragma unroll
        for (int n = 0; n < 2; ++n)
            #pragma unroll
            for (int j = 0; j < 4; ++j) {
                int row = wr * 32 + m * 16 + ((lane >> 4) << 2) + j;
                int col = wc * 32 + n * 16 + (lane & 15);
                Ct[row * 64 + col] = acc[m][n][j];   // 2-way bank alias: free
            }
    __syncthreads();

    float mx = 0.0f;
    #pragma unroll
    for (int it = 0; it < 4; ++it) {
        int r = wave * 16 + it * 4 + (lane >> 4);
        int c = (lane & 15) * 4;
        f32x4 v = *reinterpret_cast<f32x4*>(&Ct[r * 64 + c]);
        #pragma unroll
        for (int j = 0; j < 4; ++j) {
            float s = 1.0f - v[j];
            mx = fmaxf(mx, fmaxf(s * s, (s - 1.0f) * (s - 1.0f)));
        }
        size_t o = (size_t)(brow + r) * Nn + bcol + c;
        *reinterpret_cast<f32x4*>(&dist[o]) = v;    // DIST ONLY (scor moved out)
    }

    #pragma unroll
    for (int off = 32; off; off >>= 1) mx = fmaxf(mx, __shfl_xor(mx, off));
    if (lane == 0) wmax[wave] = mx;
    __syncthreads();
    if (t == 0) {
        float m2 = wmax[0];
        #pragma unroll
        for (int w = 1; w < 8; ++w) m2 = fmaxf(m2, wmax[w]);
        bmax[blockIdx.y * gridDim.x + blockIdx.x] = m2;
    }
}

// One block (256 threads) per query row.  Reads the dist row (contiguous),
// derives scor = 1 - dist and streams it out (nontemporal, contiguous),
// then solves the 2-column Sinkhorn fixed point:
// rho <- rho*(nu1/nu0)*W/(n-W),  W(rho)=sum_i 1/(1+rho*R_i),
// R_i = exp((2*s_i-1)/(M*EPS)).  Output: top_k_i = 1/(1+rho*R_i), masked.
__global__ __launch_bounds__(256) void sinkhorn_kernel(
    const float* __restrict__ dist, float* __restrict__ scor,
    float* __restrict__ out0,
    const float* __restrict__ bmax, int Nn, int nBmax)
{
    const int b = blockIdx.x;
    const int t = threadIdx.x;
    const int lane = t & 63;
    const int wave = t >> 6;
    __shared__ float sred[4];
    __shared__ float srho;
    __shared__ float sM;

    // global C.max from per-block maxima (L2-resident)
    float m = 0.0f;
    for (int i = t; i < nBmax; i += 256) m = fmaxf(m, bmax[i]);
    #pragma unroll
    for (int off = 32; off; off >>= 1) m = fmaxf(m, __shfl_xor(m, off));
    if (lane == 0) sred[wave] = m;
    __syncthreads();
    if (t == 0) sM = fmaxf(fmaxf(sred[0], sred[1]), fmaxf(sred[2], sred[3]));
    __syncthreads();
    const float Mmax = sM;

    const float invME = 1.0f / (Mmax * EPS);
    const float nuRatio = (float)(Nn - KSEL) / (float)KSEL;
    const float fn = (float)Nn;

    const float* drow = dist + (size_t)b * Nn;
    float* srow = scor + (size_t)b * Nn;
    float R[16];
    #pragma unroll
    for (int i = 0; i < 4; ++i) {
        f32x4 v4 = *reinterpret_cast<const f32x4*>(&drow[(i * 256 + t) * 4]);
        f32x4 s4;
        #pragma unroll
        for (int j = 0; j < 4; ++j) {
            float s = 1.0f - v4[j];
            s4[j] = s;
            R[i * 4 + j] = __expf((2.0f * s - 1.0f) * invME);
        }
        __builtin_nontemporal_store(s4,
            reinterpret_cast<f32x4*>(&srow[(i * 256 + t) * 4]));
    }

    float rho = 1.0f;   // g0 = g1 = 0 initial condition
    for (int it = 0; it < 12; ++it) {
        float w = 0.0f;
        #pragma unroll
        for (int i = 0; i < 16; ++i)
            w += __builtin_amdgcn_rcpf(fmaf(rho, R[i], 1.0f));
        #pragma unroll
        for (int off = 32; off; off >>= 1) w += __shfl_xor(w, off);
        if (lane == 0) sred[wave] = w;
        __syncthreads();
        if (t == 0) {
            float W = sred[0] + sred[1] + sred[2] + sred[3];
            srho = rho * nuRatio * W / (fn - W);
        }
        __syncthreads();
        rho = srho;
    }

    float* orow = out0 + (size_t)b * Nn;
    #pragma unroll
    for (int i = 0; i < 4; ++i) {
        f32x4 v4;
        #pragma unroll
        for (int j = 0; j < 4; ++j) {
            float v = 1.0f / fmaf(rho, R[i * 4 + j], 1.0f);
            v4[j] = (v < 0.3f) ? 0.0f : v;
        }
        __builtin_nontemporal_store(v4,
            reinterpret_cast<f32x4*>(&orow[(i * 256 + t) * 4]));
    }
}

extern "C" void kernel_launch(void* const* d_in, const int* in_sizes, int n_in,
                              void* d_out, int out_size, void* d_ws, size_t ws_size,
                              hipStream_t stream) {
    const float* Q  = (const float*)d_in[0];
    const float* Nb = (const float*)d_in[1];
    const int Mrows = in_sizes[0] / KD;   // 2048
    const int Nn    = in_sizes[1] / KD;   // 4096

    float* out0 = (float*)d_out;                       // top_k_seq
    float* dist = out0 + (size_t)Mrows * Nn;           // distances
    float* scor = dist + (size_t)Mrows * Nn;           // scores
    float* bmax = (float*)d_ws;                        // per-block maxima

    dim3 g1(Nn / 64, Mrows / 128);                     // 64 x 16 = 1024 blocks
    gemm_kernel<<<g1, 512, 0, stream>>>(Q, Nb, dist, bmax, Nn);
    sinkhorn_kernel<<<Mrows, 256, 0, stream>>>(dist, scor, out0, bmax, Nn,
                                               g1.x * g1.y);
}